// Round 1
// baseline (234.233 us; speedup 1.0000x reference)
//
#include <hip/hip_runtime.h>

// FusedMHC: M = exp(x) for each 8x8 lane-mixing block, then 5 Sinkhorn-Knopp
// iterations (row normalize, then col normalize). One thread owns one 8x8
// matrix entirely in registers (64 VGPRs) -> no LDS, no cross-lane traffic.
// Memory-bound: ~1.07 GB total HBM traffic, floor ~170us @ 6.3 TB/s.

constexpr int MHC_ITERS = 5;

__global__ __launch_bounds__(256)
void fused_mhc_kernel(const float* __restrict__ x,
                      float* __restrict__ out,
                      int nmat) {
    int t = blockIdx.x * blockDim.x + threadIdx.x;
    if (t >= nmat) return;

    const float4* __restrict__ src = reinterpret_cast<const float4*>(x) + (size_t)t * 16;
    float4* __restrict__ dst = reinterpret_cast<float4*>(out) + (size_t)t * 16;

    float M[64];

    // Load 8x8 matrix as 16 x float4 (256 contiguous bytes per thread).
    #pragma unroll
    for (int k = 0; k < 16; ++k) {
        float4 v = src[k];
        M[k * 4 + 0] = v.x;
        M[k * 4 + 1] = v.y;
        M[k * 4 + 2] = v.z;
        M[k * 4 + 3] = v.w;
    }

    // exp via native v_exp_f32 path.
    #pragma unroll
    for (int i = 0; i < 64; ++i) M[i] = __expf(M[i]);

    // Sinkhorn-Knopp iterations, fully in registers.
    #pragma unroll
    for (int it = 0; it < MHC_ITERS; ++it) {
        // Row normalize: M[r][c] /= sum_c M[r][c]
        #pragma unroll
        for (int r = 0; r < 8; ++r) {
            float s = 0.0f;
            #pragma unroll
            for (int c = 0; c < 8; ++c) s += M[r * 8 + c];
            float inv = __builtin_amdgcn_rcpf(s);  // v_rcp_f32, ~1ulp
            #pragma unroll
            for (int c = 0; c < 8; ++c) M[r * 8 + c] *= inv;
        }
        // Col normalize: M[r][c] /= sum_r M[r][c]
        #pragma unroll
        for (int c = 0; c < 8; ++c) {
            float s = 0.0f;
            #pragma unroll
            for (int r = 0; r < 8; ++r) s += M[r * 8 + c];
            float inv = __builtin_amdgcn_rcpf(s);
            #pragma unroll
            for (int r = 0; r < 8; ++r) M[r * 8 + c] *= inv;
        }
    }

    // Store back, 16 x float4.
    #pragma unroll
    for (int k = 0; k < 16; ++k) {
        float4 v;
        v.x = M[k * 4 + 0];
        v.y = M[k * 4 + 1];
        v.z = M[k * 4 + 2];
        v.w = M[k * 4 + 3];
        dst[k] = v;
    }
}

extern "C" void kernel_launch(void* const* d_in, const int* in_sizes, int n_in,
                              void* d_out, int out_size, void* d_ws, size_t ws_size,
                              hipStream_t stream) {
    const float* x = (const float*)d_in[0];
    float* out = (float*)d_out;

    const int nmat = in_sizes[0] / 64;  // number of 8x8 matrices
    const int threads = 256;
    const int blocks = (nmat + threads - 1) / threads;

    fused_mhc_kernel<<<blocks, threads, 0, stream>>>(x, out, nmat);
}

// Round 2
// 205.885 us; speedup vs baseline: 1.1377x; 1.1377x over previous
//
#include <hip/hip_runtime.h>

// FusedMHC: per 8x8 block, M = exp(x), then 5 Sinkhorn-Knopp iterations.
// One thread owns one matrix in registers. Global I/O is staged through LDS
// so both load and store are dense wave-coalesced float4 streams; the
// 256B-stride matrix gather/scatter happens in LDS with an XOR bank swizzle.
//
// Swizzle: float4 index g (matrix m = g>>4, sub k = g&15) lives at LDS slot
// g ^ (m & 15)  (XOR confined to the k-field -> bijective per matrix).
// Per-wave this spreads both the coalesced stage passes and the per-thread
// matrix reads across 8 lanes/bank-group = the ds_*_b128 minimum.

constexpr int MHC_ITERS = 5;
constexpr int THREADS = 128;           // one matrix per thread
constexpr int F4_PER_BLOCK = THREADS * 16;  // 2048 float4 = 32 KB LDS

__global__ __launch_bounds__(THREADS)
void fused_mhc_kernel(const float* __restrict__ x,
                      float* __restrict__ out,
                      int nmat) {
    __shared__ float4 lds[F4_PER_BLOCK];

    const int t = threadIdx.x;
    const size_t mat0 = (size_t)blockIdx.x * THREADS;
    const float4* __restrict__ src = reinterpret_cast<const float4*>(x) + mat0 * 16;
    float4* __restrict__ dst = reinterpret_cast<float4*>(out) + mat0 * 16;

    // ---- Stage in: coalesced global -> swizzled LDS (16 x 2KB passes) ----
    #pragma unroll
    for (int p = 0; p < 16; ++p) {
        int g = p * THREADS + t;
        int s = g ^ ((g >> 4) & 15);
        lds[s] = src[g];
    }
    __syncthreads();

    // ---- Gather own matrix from LDS ----
    float M[64];
    const int mlow = t & 15;
    #pragma unroll
    for (int k = 0; k < 16; ++k) {
        float4 v = lds[t * 16 + (k ^ mlow)];
        M[k * 4 + 0] = v.x;
        M[k * 4 + 1] = v.y;
        M[k * 4 + 2] = v.z;
        M[k * 4 + 3] = v.w;
    }

    // ---- exp + Sinkhorn-Knopp, fully in registers ----
    #pragma unroll
    for (int i = 0; i < 64; ++i) M[i] = __expf(M[i]);

    #pragma unroll
    for (int it = 0; it < MHC_ITERS; ++it) {
        #pragma unroll
        for (int r = 0; r < 8; ++r) {
            float s = 0.0f;
            #pragma unroll
            for (int c = 0; c < 8; ++c) s += M[r * 8 + c];
            float inv = __builtin_amdgcn_rcpf(s);
            #pragma unroll
            for (int c = 0; c < 8; ++c) M[r * 8 + c] *= inv;
        }
        #pragma unroll
        for (int c = 0; c < 8; ++c) {
            float s = 0.0f;
            #pragma unroll
            for (int r = 0; r < 8; ++r) s += M[r * 8 + c];
            float inv = __builtin_amdgcn_rcpf(s);
            #pragma unroll
            for (int r = 0; r < 8; ++r) M[r * 8 + c] *= inv;
        }
    }

    // ---- Scatter own matrix back to its (private) swizzled LDS slots ----
    #pragma unroll
    for (int k = 0; k < 16; ++k) {
        float4 v;
        v.x = M[k * 4 + 0];
        v.y = M[k * 4 + 1];
        v.z = M[k * 4 + 2];
        v.w = M[k * 4 + 3];
        lds[t * 16 + (k ^ mlow)] = v;
    }
    __syncthreads();

    // ---- Stage out: swizzled LDS -> coalesced global ----
    #pragma unroll
    for (int p = 0; p < 16; ++p) {
        int g = p * THREADS + t;
        int s = g ^ ((g >> 4) & 15);
        dst[g] = lds[s];
    }
}

extern "C" void kernel_launch(void* const* d_in, const int* in_sizes, int n_in,
                              void* d_out, int out_size, void* d_ws, size_t ws_size,
                              hipStream_t stream) {
    const float* x = (const float*)d_in[0];
    float* out = (float*)d_out;

    const int nmat = in_sizes[0] / 64;           // 8x8 matrices
    const int blocks = nmat / THREADS;           // 2,097,152 / 128 = 16384

    fused_mhc_kernel<<<blocks, THREADS, 0, stream>>>(x, out, nmat);
}

// Round 4
// 190.217 us; speedup vs baseline: 1.2314x; 1.0824x over previous
//
#include <hip/hip_runtime.h>

// FusedMHC: per 8x8 block, M = exp(x), then 5 Sinkhorn-Knopp iterations.
// 4 threads per matrix; each thread owns 2 rows (16 floats) in registers.
// - Global I/O staged through LDS (coalesced float4 streams both ways).
// - LDS swizzle: float4 index g lives at slot g ^ ((g>>4)&15). Stage passes
//   are conflict-free; per-thread gather/scatter is <=2-way (free).
// - Row normalize: thread-local. Col normalize: quad butterfly via DPP
//   quad_perm (v_add_f32 + dpp, no DS pipe, no barrier).
// - 64 B LDS/thread -> wave-cap-limited occupancy: 8 blocks/CU, 32 waves/CU.

constexpr int MHC_ITERS = 5;
constexpr int THREADS = 256;
constexpr int MATS_PER_BLOCK = THREADS / 4;        // 64 matrices/block
constexpr int F4_PER_BLOCK = MATS_PER_BLOCK * 16;  // 1024 float4 = 16 KB

// dpp_ctrl must be a compile-time constant -> template parameter.
template <int CTRL>
__device__ __forceinline__ float quad_xor_add(float x) {
    int peer = __builtin_amdgcn_update_dpp(0, __float_as_int(x), CTRL, 0xF, 0xF, true);
    return x + __int_as_float(peer);
}

__global__ __launch_bounds__(THREADS)
void fused_mhc_kernel(const float* __restrict__ x, float* __restrict__ out) {
    __shared__ float4 lds[F4_PER_BLOCK];

    const int t = threadIdx.x;
    const size_t base = (size_t)blockIdx.x * F4_PER_BLOCK;
    const float4* __restrict__ src = reinterpret_cast<const float4*>(x) + base;
    float4* __restrict__ dst = reinterpret_cast<float4*>(out) + base;

    // ---- Stage in: coalesced global -> swizzled LDS (4 passes) ----
    #pragma unroll
    for (int p = 0; p < 4; ++p) {
        int g = p * THREADS + t;
        lds[g ^ ((g >> 4) & 15)] = src[g];
    }
    __syncthreads();

    // ---- Gather: thread (m,h) owns rows 2h, 2h+1 of local matrix m ----
    const int m = t >> 2;
    const int h = t & 3;
    const int swz = m & 15;

    float M[16];  // M[0..7] = row 2h, M[8..15] = row 2h+1
    #pragma unroll
    for (int j = 0; j < 4; ++j) {
        float4 v = lds[(m * 16 + h * 4 + j) ^ swz];
        M[j * 4 + 0] = v.x;
        M[j * 4 + 1] = v.y;
        M[j * 4 + 2] = v.z;
        M[j * 4 + 3] = v.w;
    }

    #pragma unroll
    for (int i = 0; i < 16; ++i) M[i] = __expf(M[i]);

    #pragma unroll
    for (int it = 0; it < MHC_ITERS; ++it) {
        // Row normalize (both rows fully local).
        #pragma unroll
        for (int r = 0; r < 2; ++r) {
            float s = 0.0f;
            #pragma unroll
            for (int c = 0; c < 8; ++c) s += M[r * 8 + c];
            float inv = __builtin_amdgcn_rcpf(s);
            #pragma unroll
            for (int c = 0; c < 8; ++c) M[r * 8 + c] *= inv;
        }
        // Col normalize: per-thread partials, quad butterfly via DPP.
        // 0xB1 = quad_perm [1,0,3,2] (xor 1), 0x4E = quad_perm [2,3,0,1] (xor 2).
        #pragma unroll
        for (int c = 0; c < 8; ++c) {
            float part = M[c] + M[8 + c];
            part = quad_xor_add<0xB1>(part);
            part = quad_xor_add<0x4E>(part);
            float inv = __builtin_amdgcn_rcpf(part);
            M[c] *= inv;
            M[8 + c] *= inv;
        }
    }

    // ---- Scatter back to own (private) swizzled slots ----
    #pragma unroll
    for (int j = 0; j < 4; ++j) {
        float4 v;
        v.x = M[j * 4 + 0];
        v.y = M[j * 4 + 1];
        v.z = M[j * 4 + 2];
        v.w = M[j * 4 + 3];
        lds[(m * 16 + h * 4 + j) ^ swz] = v;
    }
    __syncthreads();

    // ---- Stage out: swizzled LDS -> coalesced global ----
    #pragma unroll
    for (int p = 0; p < 4; ++p) {
        int g = p * THREADS + t;
        dst[g] = lds[g ^ ((g >> 4) & 15)];
    }
}

extern "C" void kernel_launch(void* const* d_in, const int* in_sizes, int n_in,
                              void* d_out, int out_size, void* d_ws, size_t ws_size,
                              hipStream_t stream) {
    const float* x = (const float*)d_in[0];
    float* out = (float*)d_out;

    const int nmat = in_sizes[0] / 64;                // 8x8 matrices
    const int blocks = nmat / MATS_PER_BLOCK;         // 2,097,152 / 64 = 32768

    fused_mhc_kernel<<<blocks, THREADS, 0, stream>>>(x, out);
}